// Round 14
// baseline (117.667 us; speedup 1.0000x reference)
//
#include <hip/hip_runtime.h>

typedef unsigned short u16;
typedef short bf16x8 __attribute__((ext_vector_type(8)));
typedef float f32x4 __attribute__((ext_vector_type(4)));
typedef u16 u16x4 __attribute__((ext_vector_type(4)));

__device__ __forceinline__ float b2f(u16 h) {
  unsigned u = ((unsigned)h) << 16;
  return __builtin_bit_cast(float, u);
}
// native RTNE f32->bf16; compiler pairs these into v_cvt_pk_bf16_f32
__device__ __forceinline__ u16 f2b(float f) {
  return __builtin_bit_cast(u16, (__bf16)f);
}
__device__ __forceinline__ void gld_lds16(const void* g, void* l) {
  __builtin_amdgcn_global_load_lds(
      (__attribute__((address_space(1))) void*)(g),
      (__attribute__((address_space(3))) void*)(l), 16, 0, 0);
}

// ---------------------------------------------------------------------------
// prep (R6-exact): blocks [0,160): fp32 weights -> bf16 STAGED
//   [layer][s8(32)][m(256)][8]; layers: 0,1 = post_w; 2,3,4 = pre_w
// blocks [160,416): x [2][256][1024] fp32 -> xt [2048][256] bf16 (transpose)
// ---------------------------------------------------------------------------
__global__ void dense_edge_prep(const float* __restrict__ x,
                                const float* __restrict__ pre_w,
                                const float* __restrict__ post_w,
                                u16* __restrict__ wb, u16* __restrict__ xt) {
  const int blk = blockIdx.x;
  const int t = threadIdx.x;
  if (blk < 160) {
    const int id = blk * 256 + t;      // 40960 slots of 8 elems
    const int layer = id >> 13;        // 0..4
    const int sid = id & 8191;
    const int m = sid >> 5;
    const int s8 = sid & 31;
    const float* src = (layer < 2) ? (post_w + layer * 65536)
                                   : (pre_w + (layer - 2) * 65536);
    u16* dst = wb + layer * 65536;
    f32x4 a = *(const f32x4*)(src + m * 256 + s8 * 8);
    f32x4 c = *(const f32x4*)(src + m * 256 + s8 * 8 + 4);
    bf16x8 o;
#pragma unroll
    for (int j = 0; j < 4; j++) o[j] = (short)f2b(a[j]);
#pragma unroll
    for (int j = 0; j < 4; j++) o[4 + j] = (short)f2b(c[j]);
    *(bf16x8*)(dst + (s8 * 256 + m) * 8) = o;
  } else {
    __shared__ float tile[32 * 65];
    const int xb = blk - 160;          // 2 b x 8 ctile x 16 hwtile = 256
    const int b = xb >> 7;
    const int ct = (xb >> 4) & 7;
    const int ht = xb & 15;
    const int c0 = ct * 32, hw0 = ht * 64;
#pragma unroll
    for (int rep = 0; rep < 8; rep++) {
      const int idx = rep * 256 + t;
      const int cl = idx >> 6, hl = idx & 63;
      tile[cl * 65 + hl] = x[(b * 256 + c0 + cl) * 1024 + hw0 + hl];
    }
    __syncthreads();
    const int hl = t >> 2, c8 = t & 3;
    bf16x8 o;
#pragma unroll
    for (int i = 0; i < 8; i++) o[i] = (short)f2b(tile[(c8 * 8 + i) * 65 + hl]);
    *(bf16x8*)(xt + (b * 1024 + hw0 + hl) * 256 + c0 + c8 * 8) = o;
  }
}

// ---------------------------------------------------------------------------
// pre (R6-exact): 3-layer 1x1-conv chain on 2048 nodes, bf16 MFMA.
// ---------------------------------------------------------------------------
__global__ __launch_bounds__(256, 2) void dense_edge_pre(
    const u16* __restrict__ xt, const u16* __restrict__ wpre,
    const float* __restrict__ preb, u16* __restrict__ flat) {
  __shared__ u16 feat[2][4096];  // [32 s8][16 n][8] each
  const int t = threadIdx.x;
  const int wv = t >> 6, ln = t & 63;
  const int nb = blockIdx.x * 16;
  const int q4 = ln >> 4, r15 = ln & 15;

#pragma unroll
  for (int i = 0; i < 2; i++) {
    const int slot = wv * 128 + i * 64 + ln;
    const int s8 = slot >> 4, nl = slot & 15;
    gld_lds16(xt + (nb + nl) * 256 + s8 * 8, &feat[0][slot * 8]);
  }
  __syncthreads();

#pragma unroll
  for (int l = 0; l < 3; l++) {
    const u16* wl = wpre + l * 65536;
    f32x4 acc[4];
    f32x4 zero = {0.f, 0.f, 0.f, 0.f};
#pragma unroll
    for (int mt = 0; mt < 4; mt++) acc[mt] = zero;
#pragma unroll
    for (int s = 0; s < 8; s++) {
      bf16x8 bv = *(const bf16x8*)(&feat[l & 1][((s * 4 + q4) * 16 + r15) * 8]);
#pragma unroll
      for (int mt = 0; mt < 4; mt++) {
        bf16x8 av = *(const bf16x8*)(wl + ((s * 4 + q4) * 256 + wv * 64 + mt * 16 + r15) * 8);
        acc[mt] = __builtin_amdgcn_mfma_f32_16x16x32_bf16(av, bv, acc[mt], 0, 0, 0);
      }
    }
    if (l < 2) {
#pragma unroll
      for (int mt = 0; mt < 4; mt++) {
        const int o = wv * 64 + mt * 16 + q4 * 4;
        f32x4 bb = *(const f32x4*)(preb + l * 256 + o);
        u16x4 pk;
#pragma unroll
        for (int r = 0; r < 4; r++) {
          float v = fmaxf(acc[mt][r] + bb[r], 0.f);
          pk[r] = f2b(v);
        }
        *(u16x4*)(&feat[(l + 1) & 1][((o >> 3) * 16 + r15) * 8 + (o & 7)]) = pk;
      }
      __syncthreads();
    } else {
#pragma unroll
      for (int mt = 0; mt < 4; mt++) {
        const int o = wv * 64 + mt * 16 + q4 * 4;
        f32x4 bb = *(const f32x4*)(preb + 512 + o);
        u16x4 pk;
#pragma unroll
        for (int r = 0; r < 4; r++) pk[r] = f2b(acc[mt][r] + bb[r]);  // no relu
        *(u16x4*)(flat + (nb + r15) * 256 + o) = pk;
      }
    }
  }
}

// ---------------------------------------------------------------------------
// main v11 = v9 (role-split mt=4/nt=2, best measured 42.3 us) with TWO tiles
// per phase and 4-deep buffers: 11 barriers instead of 18. Tests the last
// unfalsified theory: per-phase fixed overhead (barrier drain + wave resync).
// All per-tile work, layouts, and register footprints identical to v9.
// Buffer parity = tile & 3; same-phase reads/writes verified disjoint:
//   phase k: G1(2k),G1(2k+1) read xx[2k&3],[2k+1&3]; XX writes [2k+2&3],
//   [2k+3&3]; G2 reads t1[2k-2&3],[2k-1&3] (written prev phase); q-gather
//   writes qstage[2k&3],[2k+1&3] while XX reads [2k+2&3],[2k+3&3].
// LDS: xx 4x16K + t1 4x16K + pstage 4K + qstage 4x2K + pbuf 4K = 144 KB.
// ---------------------------------------------------------------------------
#define NTILE 16
__global__ __launch_bounds__(512, 2) void dense_edge_main(
    const u16* __restrict__ flat, const int* __restrict__ pidx,
    const int* __restrict__ cidx, const u16* __restrict__ w1s,
    const u16* __restrict__ w2s, const float* __restrict__ b1,
    const float* __restrict__ b2, const float* __restrict__ w3,
    const float* __restrict__ b3, float* __restrict__ out) {
  __shared__ u16 xxbuf[4][8192];    // [par][cc(32)][n(32)][8]  4x16 KB
  __shared__ u16 t1buf[4][8192];    // same layout              4x16 KB
  __shared__ u16 pstage[2048];      // [cc(32)][p(8)][8]        4 KB
  __shared__ u16 qstage[4][1024];   // [par][cc(32)][q(4)][8]   4x2 KB
  __shared__ float pbuf[4][4][2][32];// [par][cw][o3][n]        4 KB

  const int t = threadIdx.x;
  const int wv = t >> 6;
  const int ln = t & 63;
  const int q4 = ln >> 4, r15 = ln & 15;
  const bool prod = wv < 4;
  const int cw = wv & 3;
  const int blk = blockIdx.x;
  const int b = blk >> 7;            // 128 blocks per batch
  const int pt = (blk >> 2) & 31;
  const int qg = blk & 3;
  const int p0 = pt * 8;
  const int q0 = qg * 64;

  // role weights: 64 m-rows per wave (4 waves cover 256) from staged layout
  const u16* wsrc = prod ? w1s : w2s;
  bf16x8 af[4][8];
#pragma unroll
  for (int s = 0; s < 8; s++)
#pragma unroll
    for (int mt = 0; mt < 4; mt++)
      af[mt][s] = *(const bf16x8*)(wsrc + ((s * 4 + q4) * 256 + cw * 64 + mt * 16 + r15) * 8);

  // init staging: producers -> pstage; consumer wave (4+i) -> qstage tile i
  if (prod) {
    const int slot = cw * 64 + ln;           // 0..255
    const int prow = slot & 7, cc = slot >> 3;
    const int pn = pidx[b * 256 + p0 + prow];
    gld_lds16(flat + pn * 256 + cc * 8, &pstage[slot * 8]);
  } else {
    const int tile = wv - 4;                 // tiles 0..3
    const int qn = cidx[b * 256 + q0 + tile * 4 + (ln & 3)];
    gld_lds16(flat + qn * 256 + (ln >> 2) * 8, &qstage[tile][ln * 8]);
    gld_lds16(flat + qn * 256 + (16 + (ln >> 2)) * 8,
              &qstage[tile][(64 + ln) * 8]);
  }
  // q-index preload for tiles 4 (wv6) and 5 (wv7)
  int qn_cur = 0;
  if (wv >= 6) qn_cur = cidx[b * 256 + q0 + (4 + (wv - 6)) * 4 + (ln & 3)];
  __syncthreads();

  // producers: hoist p-row fragments (constant across all 16 tiles)
  const int nn32 = ln & 31;
  const int half32 = ln >> 5;
  bf16x8 pa[4];
  if (prod) {
#pragma unroll
    for (int i = 0; i < 4; i++) {
      const int cc = cw * 8 + half32 * 4 + i;
      pa[i] = *(const bf16x8*)(&pstage[((cc * 8 + (nn32 >> 2))) * 8]);
    }
  }

  // ---- producer: XX build for tile jx ----
  auto do_xx = [&](int jx) {
    const u16* qs = qstage[jx & 3];
    u16* xb = xxbuf[jx & 3];
#pragma unroll
    for (int i = 0; i < 4; i++) {
      const int cc = cw * 8 + half32 * 4 + i;
      bf16x8 av = pa[i];
      bf16x8 bv = *(const bf16x8*)(&qs[(cc * 4 + (nn32 & 3)) * 8]);
      bf16x8 ov;
#pragma unroll
      for (int jj = 0; jj < 8; jj++) {
        float d = b2f((u16)av[jj]) - b2f((u16)bv[jj]);
        ov[jj] = (short)f2b(d * d);
      }
      *(bf16x8*)(&xb[(cc * 32 + nn32) * 8]) = ov;
    }
  };

  // ---- producer: GEMM1 (64 MFMA) + relu/b1 pack -> t1buf ----
  auto do_g1 = [&](int jg) {
    const u16* xb = xxbuf[jg & 3];
    f32x4 acc[4][2];
    {
      f32x4 zero = {0.f, 0.f, 0.f, 0.f};
#pragma unroll
      for (int mt = 0; mt < 4; mt++)
#pragma unroll
        for (int nt = 0; nt < 2; nt++) acc[mt][nt] = zero;
    }
    __builtin_amdgcn_s_setprio(1);
#pragma unroll
    for (int s = 0; s < 8; s++) {
      bf16x8 bfr[2];
#pragma unroll
      for (int nt = 0; nt < 2; nt++)
        bfr[nt] = *(const bf16x8*)(xb + ((s * 4 + q4) * 32 + nt * 16 + r15) * 8);
#pragma unroll
      for (int mt = 0; mt < 4; mt++)
#pragma unroll
        for (int nt = 0; nt < 2; nt++)
          acc[mt][nt] = __builtin_amdgcn_mfma_f32_16x16x32_bf16(af[mt][s], bfr[nt], acc[mt][nt], 0, 0, 0);
    }
    __builtin_amdgcn_s_setprio(0);
#pragma unroll
    for (int mt = 0; mt < 4; mt++) {
      const int o = cw * 64 + mt * 16 + q4 * 4;
      f32x4 bb = *(const f32x4*)(b1 + o);
#pragma unroll
      for (int nt = 0; nt < 2; nt++) {
        const int n = nt * 16 + r15;
        u16x4 pk;
#pragma unroll
        for (int r = 0; r < 4; r++) {
          float v = fmaxf(acc[mt][nt][r] + bb[r], 0.f);
          pk[r] = f2b(v);
        }
        *(u16x4*)(&t1buf[jg & 3][((o >> 3) * 32 + n) * 8 + (o & 7)]) = pk;
      }
    }
  };

  // ---- consumer: GEMM2 (64 MFMA) + W3 epilogue -> pbuf ----
  auto do_g2 = [&](int jg) {
    const u16* tb = t1buf[jg & 3];
    f32x4 acc[4][2];
    {
      f32x4 zero = {0.f, 0.f, 0.f, 0.f};
#pragma unroll
      for (int mt = 0; mt < 4; mt++)
#pragma unroll
        for (int nt = 0; nt < 2; nt++) acc[mt][nt] = zero;
    }
    __builtin_amdgcn_s_setprio(1);
#pragma unroll
    for (int s = 0; s < 8; s++) {
      bf16x8 bfr[2];
#pragma unroll
      for (int nt = 0; nt < 2; nt++)
        bfr[nt] = *(const bf16x8*)(tb + ((s * 4 + q4) * 32 + nt * 16 + r15) * 8);
#pragma unroll
      for (int mt = 0; mt < 4; mt++)
#pragma unroll
        for (int nt = 0; nt < 2; nt++)
          acc[mt][nt] = __builtin_amdgcn_mfma_f32_16x16x32_bf16(af[mt][s], bfr[nt], acc[mt][nt], 0, 0, 0);
    }
    __builtin_amdgcn_s_setprio(0);
    float part[2][2] = {{0.f, 0.f}, {0.f, 0.f}};
#pragma unroll
    for (int mt = 0; mt < 4; mt++) {
      const int o = cw * 64 + mt * 16 + q4 * 4;
      f32x4 bb = *(const f32x4*)(b2 + o);
      f32x4 w3a = *(const f32x4*)(w3 + o);
      f32x4 w3b = *(const f32x4*)(w3 + 256 + o);
#pragma unroll
      for (int nt = 0; nt < 2; nt++) {
#pragma unroll
        for (int r = 0; r < 4; r++) {
          float v = fmaxf(acc[mt][nt][r] + bb[r], 0.f);
          part[0][nt] += v * w3a[r];
          part[1][nt] += v * w3b[r];
        }
      }
    }
#pragma unroll
    for (int o3 = 0; o3 < 2; o3++)
#pragma unroll
      for (int nt = 0; nt < 2; nt++) {
        part[o3][nt] += __shfl_xor(part[o3][nt], 16, 64);
        part[o3][nt] += __shfl_xor(part[o3][nt], 32, 64);
      }
    if (q4 == 0) {
#pragma unroll
      for (int o3 = 0; o3 < 2; o3++)
#pragma unroll
        for (int nt = 0; nt < 2; nt++)
          pbuf[jg & 3][cw][o3][nt * 16 + r15] = part[o3][nt];
    }
  };

  // ---- consumer wave 4: output store for tile jo ----
  auto do_out = [&](int jo) {
    const int o3 = ln >> 5, n = ln & 31;
    float v = b3[o3];
#pragma unroll
    for (int k = 0; k < 4; k++) v += pbuf[jo & 3][k][o3][n];
    out[((b * 2 + o3) * 256 + p0 + (n >> 2)) * 256 + q0 + jo * 4 + (n & 3)] = v;
  };

  // prologue: producers build XX(0), XX(1) (qstage 0,1 staged at init)
  if (prod) {
    do_xx(0);
    do_xx(1);
  }
  __syncthreads();

#pragma unroll 1
  for (int k = 0; k <= 8; k++) {
    const int j0 = 2 * k;
    if (prod) {
      if (j0 < NTILE) do_g1(j0);
      if (j0 + 1 < NTILE) do_g1(j0 + 1);
      if (j0 + 2 < NTILE) do_xx(j0 + 2);
      if (j0 + 3 < NTILE) do_xx(j0 + 3);
    } else {
      if (wv == 4) {
        if (j0 >= 4) do_out(j0 - 4);
        if (j0 >= 3) do_out(j0 - 3);
      }
      if (wv >= 6) {
        const int jt = j0 + 4 + (wv - 6);
        if (jt < NTILE) {
          gld_lds16(flat + qn_cur * 256 + (ln >> 2) * 8,
                    &qstage[jt & 3][ln * 8]);
          gld_lds16(flat + qn_cur * 256 + (16 + (ln >> 2)) * 8,
                    &qstage[jt & 3][(64 + ln) * 8]);
          if (jt + 2 < NTILE)
            qn_cur = cidx[b * 256 + q0 + (jt + 2) * 4 + (ln & 3)];
        }
      }
      if (j0 >= 2) do_g2(j0 - 2);
      if (j0 >= 1 && j0 - 1 < NTILE) do_g2(j0 - 1);
    }
    __syncthreads();
  }

  // epilogue: out(14), out(15)
  if (wv == 4) {
    do_out(NTILE - 2);
    do_out(NTILE - 1);
  }
}

// ---------------------------------------------------------------------------
extern "C" void kernel_launch(void* const* d_in, const int* in_sizes, int n_in,
                              void* d_out, int out_size, void* d_ws, size_t ws_size,
                              hipStream_t stream) {
  (void)in_sizes; (void)n_in; (void)out_size; (void)ws_size;
  const float* x          = (const float*)d_in[0];
  const int*   pidx       = (const int*)d_in[1];
  const int*   cidx       = (const int*)d_in[2];
  const float* pre_w      = (const float*)d_in[3];
  const float* pre_b      = (const float*)d_in[4];
  const float* post_w     = (const float*)d_in[5];
  const float* post_b     = (const float*)d_in[6];
  const float* post_out_w = (const float*)d_in[7];
  const float* post_out_b = (const float*)d_in[8];
  float* out = (float*)d_out;

  u16* ws   = (u16*)d_ws;
  u16* wb   = ws;              // staged bf16 weights: w1,w2,pre0,pre1,pre2
  u16* w1s  = wb;
  u16* w2s  = wb + 65536;
  u16* wpre = wb + 131072;
  u16* xt   = ws + 327680;     // x_t bf16 [2048][256]
  u16* flat = ws + 851968;     // node features bf16 [2048][256]

  dense_edge_prep<<<416, 256, 0, stream>>>(x, pre_w, post_w, wb, xt);
  dense_edge_pre<<<128, 256, 0, stream>>>(xt, wpre, pre_b, flat);
  dense_edge_main<<<256, 512, 0, stream>>>(flat, pidx, cidx, w1s, w2s,
                                           post_b, post_b + 256,
                                           post_out_w, post_out_b, out);
}